// Round 1
// baseline (191.001 us; speedup 1.0000x reference)
//
#include <hip/hip_runtime.h>
#include <math.h>

#define B 4096
#define N 10000
#define D 256
#define ALPHA 0.2f
#define RANK_SEGS 8

// --- 1) s_b = P[b]·Wp (b<B), t_n = V[n]·Wn (n<N). One 64-thread wave per row.
__global__ __launch_bounds__(64) void k_dot_scores(
    const float* __restrict__ P, const float* __restrict__ V, const float* __restrict__ K,
    float* __restrict__ t, float* __restrict__ s) {
  int j = blockIdx.x;
  int lane = threadIdx.x;
  const float* row; const float* w; float* outp; int oi;
  if (j < N) { row = V + (size_t)j * D; w = K + D; outp = t; oi = j; }
  else       { row = P + (size_t)(j - N) * D; w = K; outp = s; oi = j - N; }
  float4 r  = ((const float4*)row)[lane];
  float4 kk = ((const float4*)w)[lane];
  float acc = r.x * kk.x + r.y * kk.y + r.z * kk.z + r.w * kk.w;
  #pragma unroll
  for (int off = 32; off > 0; off >>= 1) acc += __shfl_down(acc, off, 64);
  if (lane == 0) outp[oi] = acc;
}

// --- 2) rank_n = #{m : t_m < t_n  or (t_m==t_n and m<n)} — counting sort rank.
// Split the m-range into RANK_SEGS segments for parallelism; atomicAdd partials.
__global__ __launch_bounds__(256) void k_rank_partial(
    const float* __restrict__ t, int* __restrict__ rank) {
  __shared__ float sm[256];
  int n = blockIdx.x * 256 + threadIdx.x;
  float tn = (n < N) ? t[n] : 0.f;
  int seglen = (N + RANK_SEGS - 1) / RANK_SEGS;
  int m0 = blockIdx.y * seglen;
  int m1 = min(N, m0 + seglen);
  int r = 0;
  for (int k0 = m0; k0 < m1; k0 += 256) {
    int m = k0 + threadIdx.x;
    sm[threadIdx.x] = (m < m1) ? t[m] : 0.f;
    __syncthreads();
    int lim = min(256, m1 - k0);
    for (int j = 0; j < lim; ++j) {
      float tm = sm[j];
      int mm = k0 + j;
      r += (tm < tn || (tm == tn && mm < n)) ? 1 : 0;
    }
    __syncthreads();
  }
  if (n < N && r) atomicAdd(&rank[n], r);
}

// --- 3) scatter into sorted order; precompute exp factors.
__global__ __launch_bounds__(256) void k_scatter(
    const float* __restrict__ t, const int* __restrict__ rank,
    float* __restrict__ tsort, float* __restrict__ eA, float* __restrict__ eC,
    int* __restrict__ idxs) {
  int n = blockIdx.x * 256 + threadIdx.x;
  if (n < N) {
    int r = rank[n];
    float tn = t[n];
    tsort[r] = tn;
    eA[r] = __expf(tn);
    eC[r] = __expf(ALPHA * tn);
    idxs[r] = n;
  }
}

// --- 4) prefix sums over sorted order.
// Block d (0..D-1): column d of Apre[k][d] = sum_{i<k} eA[i]*V[idxs[i]][d],
//                   Cpre likewise with eC. Block D: scalar sums a0pre/c0pre.
// Wave-shuffle inclusive scan per 256-chunk; 2 barriers per chunk.
__global__ __launch_bounds__(256) void k_scan_cols(
    const float* __restrict__ eA, const float* __restrict__ eC,
    const int* __restrict__ idxs, const float* __restrict__ V,
    float* __restrict__ Apre, float* __restrict__ Cpre,
    float* __restrict__ a0pre, float* __restrict__ c0pre) {
  int d = blockIdx.x;              // 0..D-1 vector cols; d==D -> scalar col
  int i = threadIdx.x;
  int lane = i & 63, wave = i >> 6;
  __shared__ float wsA[4], wsC[4];
  bool sc = (d == D);
  float carA = 0.f, carC = 0.f;
  if (i == 0) {
    if (sc) { a0pre[0] = 0.f; c0pre[0] = 0.f; }
    else    { Apre[d] = 0.f;  Cpre[d] = 0.f; }
  }
  for (int k0 = 0; k0 < N; k0 += 256) {
    int k = k0 + i;
    float a = 0.f, c = 0.f;
    if (k < N) {
      float ea = eA[k], ec = eC[k];
      if (sc) { a = ea; c = ec; }
      else {
        float v = V[(size_t)idxs[k] * D + d];
        a = ea * v; c = ec * v;
      }
    }
    #pragma unroll
    for (int off = 1; off < 64; off <<= 1) {
      float ta = __shfl_up(a, off, 64);
      float tc = __shfl_up(c, off, 64);
      if (lane >= off) { a += ta; c += tc; }
    }
    if (lane == 63) { wsA[wave] = a; wsC[wave] = c; }
    __syncthreads();
    float offA = carA, offC = carC;
    for (int wv = 0; wv < wave; ++wv) { offA += wsA[wv]; offC += wsC[wv]; }
    if (k < N) {
      float inA = offA + a, inC = offC + c;
      if (sc) { a0pre[k + 1] = inA; c0pre[k + 1] = inC; }
      else {
        Apre[(size_t)(k + 1) * D + d] = inA;
        Cpre[(size_t)(k + 1) * D + d] = inC;
      }
    }
    carA += wsA[0] + wsA[1] + wsA[2] + wsA[3];
    carC += wsC[0] + wsC[1] + wsC[2] + wsC[3];
    __syncthreads();
  }
}

// --- 5) per-patient: binary search for k_b = #{t_n < -s_b}, then
// out = P + (e^s * suffixA + e^{0.2s} * prefixC) / l
__global__ __launch_bounds__(256) void k_finalize(
    const float* __restrict__ P, const float* __restrict__ s,
    const float* __restrict__ tsort,
    const float* __restrict__ Apre, const float* __restrict__ Cpre,
    const float* __restrict__ a0pre, const float* __restrict__ c0pre,
    float* __restrict__ out) {
  int b = blockIdx.x, d = threadIdx.x;
  float sb = s[b];
  float key = -sb;
  int lo = 0, hi = N;             // lower_bound: first idx with tsort[idx] >= key
  while (lo < hi) {
    int mid = (lo + hi) >> 1;
    if (tsort[mid] < key) lo = mid + 1; else hi = mid;
  }
  int k = lo;
  float ea = __expf(sb), ec = __expf(ALPHA * sb);
  float l = ea * (a0pre[N] - a0pre[k]) + ec * c0pre[k];
  float va = Apre[(size_t)N * D + d] - Apre[(size_t)k * D + d];
  float vc = Cpre[(size_t)k * D + d];
  out[(size_t)b * D + d] = P[(size_t)b * D + d] + (ea * va + ec * vc) / l;
}

extern "C" void kernel_launch(void* const* d_in, const int* in_sizes, int n_in,
                              void* d_out, int out_size, void* d_ws, size_t ws_size,
                              hipStream_t stream) {
  const float* P = (const float*)d_in[0];   // (B, D)
  const float* V = (const float*)d_in[1];   // (N, D)
  const float* K = (const float*)d_in[2];   // (2D, 1)
  float* out = (float*)d_out;

  char* w = (char*)d_ws;
  float* t     = (float*)w; w += sizeof(float) * N;
  float* s     = (float*)w; w += sizeof(float) * B;
  float* tsort = (float*)w; w += sizeof(float) * N;
  float* eA    = (float*)w; w += sizeof(float) * N;
  float* eC    = (float*)w; w += sizeof(float) * N;
  int*   idxs  = (int*)w;   w += sizeof(int) * N;
  int*   rank  = (int*)w;   w += sizeof(int) * N;
  float* Apre  = (float*)w; w += sizeof(float) * (size_t)(N + 1) * D;
  float* Cpre  = (float*)w; w += sizeof(float) * (size_t)(N + 1) * D;
  float* a0pre = (float*)w; w += sizeof(float) * (N + 1);
  float* c0pre = (float*)w; w += sizeof(float) * (N + 1);
  // total ~20.9 MB of ws

  hipMemsetAsync(rank, 0, sizeof(int) * N, stream);
  k_dot_scores<<<N + B, 64, 0, stream>>>(P, V, K, t, s);
  dim3 rg((N + 255) / 256, RANK_SEGS);
  k_rank_partial<<<rg, 256, 0, stream>>>(t, rank);
  k_scatter<<<(N + 255) / 256, 256, 0, stream>>>(t, rank, tsort, eA, eC, idxs);
  k_scan_cols<<<D + 1, 256, 0, stream>>>(eA, eC, idxs, V, Apre, Cpre, a0pre, c0pre);
  k_finalize<<<B, 256, 0, stream>>>(P, s, tsort, Apre, Cpre, a0pre, c0pre, out);
}